// Round 14
// baseline (587.967 us; speedup 1.0000x reference)
//
#include <hip/hip_runtime.h>

typedef unsigned short ushort_t;
typedef unsigned int uint_t;

#define T_TOK 8192
#define HDIM 1024
#define IDIM 2048
#define NEXP 8
#define RPAD_MAX 10240                 // 8192 + 8*256 worst-case padded routed rows
#define TOTROWS (RPAD_MAX + T_TOK)     // 18432

using f32x4 = __attribute__((ext_vector_type(4))) float;
using s16x8 = __attribute__((ext_vector_type(8))) short;

#define SBAR() do { asm volatile("" ::: "memory"); __builtin_amdgcn_s_barrier(); asm volatile("" ::: "memory"); } while (0)
#define VMW(n) asm volatile("s_waitcnt vmcnt(" #n ")" ::: "memory")
#define LGKM(n) do { asm volatile("s_waitcnt lgkmcnt(" #n ")" ::: "memory"); __builtin_amdgcn_sched_barrier(0); } while (0)
#define SCHB() __builtin_amdgcn_sched_barrier(0)

__device__ __forceinline__ float b2f(ushort_t h) {
    return __uint_as_float(((uint_t)h) << 16);
}
__device__ __forceinline__ ushort_t f2bf(float f) {
    uint_t u = __float_as_uint(f);
    uint_t r = (u + 0x7FFFu + ((u >> 16) & 1u)) >> 16;
    return (ushort_t)r;
}
__device__ __forceinline__ void gload16(const void* g, void* l) {
    __builtin_amdgcn_global_load_lds(
        (const __attribute__((address_space(1))) void*)g,
        (__attribute__((address_space(3))) void*)l, 16, 0, 0);
}
// paired-row granule decode (verified rounds 4-8, 0 bank conflicts):
// granule gi -> unit=gi>>3, phys=gi&7, logical=(phys^(unit&7)) = (rowparity<<2)|kg
__device__ __forceinline__ void gdec(int gi, int& r, int& kg) {
    int prow = gi >> 3, v = (gi & 7) ^ (prow & 7);
    r = 2 * prow + (v >> 2);
    kg = v & 3;
}
// 2-D super-block scheduler (XCD locality): 4rt x 8ct rectangle per XCD round.
__device__ __forceinline__ void sbmap(int bid, int SBC, int NSB, int& rt, int& ct) {
    int x = bid & 7, j = bid >> 3;
    int r = j >> 5, pos = j & 31;
    int sb = r * 8 + x;
    int rem = NSB - r * 8;
    if (rem < 8) {
        int share = 8 / rem;
        int cap = 32 / share;
        sb = r * 8 + x / share;
        pos = (x % share) * cap + (pos % cap);
    }
    int sbr = sb / SBC, sbc = sb % SBC;
    rt = sbr * 4 + (pos >> 3);
    ct = sbc * 8 + (pos & 7);
}

// ---------------- transpose + fp32->bf16 v2: float4 reads, s16x8 writes
__global__ __launch_bounds__(256) void tcvt64(
    const float* __restrict__ gw, const float* __restrict__ shg,
    const float* __restrict__ uw, const float* __restrict__ shu,
    const float* __restrict__ dw, const float* __restrict__ shd,
    ushort_t* __restrict__ gwt, ushort_t* __restrict__ uwt,
    ushort_t* __restrict__ dwt) {
    __shared__ float tile[64][65];
    int z = blockIdx.z;
    const float* src;
    ushort_t* dst;
    int R, C, bx = blockIdx.x, by = blockIdx.y;
    if (z < 18) {
        int zz = z % 9;
        R = HDIM; C = IDIM;
        if (z < 9) { src = zz < 8 ? gw + (size_t)zz * HDIM * IDIM : shg; dst = gwt + (size_t)zz * IDIM * HDIM; }
        else       { src = zz < 8 ? uw + (size_t)zz * HDIM * IDIM : shu; dst = uwt + (size_t)zz * IDIM * HDIM; }
    } else {
        int zz = z - 18;
        R = IDIM; C = HDIM;
        src = zz < 8 ? dw + (size_t)zz * IDIM * HDIM : shd;
        dst = dwt + (size_t)zz * HDIM * IDIM;
        int t = bx; bx = by; by = t;
    }
    int c0 = bx * 64, r0 = by * 64;
    int t = threadIdx.x;
    int rrow = t >> 4, cg = (t & 15) * 4;
#pragma unroll
    for (int i = 0; i < 4; ++i) {
        int row = rrow + i * 16;
        float4 v = *(const float4*)&src[(size_t)(r0 + row) * C + c0 + cg];
        tile[row][cg] = v.x;
        tile[row][cg + 1] = v.y;
        tile[row][cg + 2] = v.z;
        tile[row][cg + 3] = v.w;
    }
    __syncthreads();
    int cw = t >> 3, rg = (t & 7) * 8;
#pragma unroll
    for (int i = 0; i < 2; ++i) {
        int c = cw + i * 32;
        s16x8 o;
#pragma unroll
        for (int j = 0; j < 8; ++j) o[j] = (short)f2bf(tile[rg + j][c]);
        *(s16x8*)&dst[(size_t)(c0 + c) * R + r0 + rg] = o;
    }
}

// ---------------- layernorm + router v2: wave-per-token, no LDS/barriers
__global__ __launch_bounds__(256) void ln_router(
    const float* __restrict__ x, const float* __restrict__ lnw,
    const float* __restrict__ lnb, const float* __restrict__ rw,
    ushort_t* __restrict__ normed, int* __restrict__ top_idx,
    float* __restrict__ top_score, int* __restrict__ cnt) {
    int w = threadIdx.x >> 6, lane = threadIdx.x & 63;
    int t = blockIdx.x * 4 + w;
    const float4* xr = (const float4*)(x + (size_t)t * HDIM);
    float4 v[4];
    float s = 0.f, ss = 0.f;
#pragma unroll
    for (int i = 0; i < 4; ++i) {
        v[i] = xr[lane + i * 64];
        s += v[i].x + v[i].y + v[i].z + v[i].w;
        ss += v[i].x * v[i].x + v[i].y * v[i].y + v[i].z * v[i].z + v[i].w * v[i].w;
    }
#pragma unroll
    for (int m = 32; m; m >>= 1) {
        s += __shfl_xor(s, m);
        ss += __shfl_xor(ss, m);
    }
    float mu = s * (1.f / HDIM);
    float rsg = rsqrtf(ss * (1.f / HDIM) - mu * mu + 1e-5f);
    float lg[8] = {0, 0, 0, 0, 0, 0, 0, 0};
#pragma unroll
    for (int i = 0; i < 4; ++i) {
        int h0 = (lane + i * 64) * 4;
        float4 lw = *(const float4*)&lnw[h0];
        float4 lb = *(const float4*)&lnb[h0];
        float xn0 = (v[i].x - mu) * rsg * lw.x + lb.x;
        float xn1 = (v[i].y - mu) * rsg * lw.y + lb.y;
        float xn2 = (v[i].z - mu) * rsg * lw.z + lb.z;
        float xn3 = (v[i].w - mu) * rsg * lw.w + lb.w;
        ushort4 o;
        o.x = f2bf(xn0); o.y = f2bf(xn1); o.z = f2bf(xn2); o.w = f2bf(xn3);
        *(ushort4*)&normed[(size_t)t * HDIM + h0] = o;
        const float* rp = rw + (size_t)h0 * NEXP;
#pragma unroll
        for (int e = 0; e < 8; ++e)
            lg[e] += xn0 * rp[e] + xn1 * rp[8 + e] + xn2 * rp[16 + e] + xn3 * rp[24 + e];
    }
#pragma unroll
    for (int m = 32; m; m >>= 1)
#pragma unroll
        for (int e = 0; e < 8; ++e) lg[e] += __shfl_xor(lg[e], m);
    if (!lane) {
        float best = -1e30f;
        int bi = 0;
#pragma unroll
        for (int e = 0; e < 8; ++e)
            if (lg[e] > best) { best = lg[e]; bi = e; }
        top_idx[t] = bi;
        top_score[t] = 1.f / (1.f + __expf(-best));
        atomicAdd(&cnt[bi], 1);
    }
}

__global__ void scan_k(const int* __restrict__ cnt, int* __restrict__ pad_off,
                       int* __restrict__ fill) {
    if (threadIdx.x == 0) {
        int o = 0;
        for (int e = 0; e < NEXP; e++) {
            pad_off[e] = o;
            o += (cnt[e] + 255) & ~255;
        }
        pad_off[NEXP] = o;
    }
    if (threadIdx.x < NEXP) fill[threadIdx.x] = 0;
}

// ---------------- scatter v2: wave-per-token, s16x8 copy
__global__ __launch_bounds__(256) void scatter_k(
    const ushort_t* __restrict__ normed, const int* __restrict__ top_idx,
    const float* __restrict__ top_score, const int* __restrict__ pad_off,
    int* __restrict__ fill, int* __restrict__ order, ushort_t* __restrict__ xs) {
    int w = threadIdx.x >> 6, lane = threadIdx.x & 63;
    int t = blockIdx.x * 4 + w;
    int p = 0;
    if (!lane) {
        int e = top_idx[t];
        p = pad_off[e] + atomicAdd(&fill[e], 1);
        order[p] = t;
    }
    p = __shfl(p, 0);
    float sc = top_score[t];
    const s16x8* src = (const s16x8*)(normed + (size_t)t * HDIM);
    s16x8* dst = (s16x8*)(xs + (size_t)p * HDIM);
#pragma unroll
    for (int j = 0; j < 2; ++j) {
        s16x8 a = src[lane + j * 64];
        s16x8 o;
#pragma unroll
        for (int k = 0; k < 8; ++k) o[k] = (short)f2bf(b2f((ushort_t)a[k]) * sc);
        dst[lane + j * 64] = o;
    }
}

// ================= GEMM1: hmid = silu(X@Wg^T)*(X@Wu^T)
// BM=256, BN=128g+128u, K-step 32, ring-4 x 32KB, COUNTED vmcnt(8) (T4),
// stages issued 3 phases ahead, ONE barrier/phase.
__global__ __launch_bounds__(512, 2) void gemm1_k(
    const ushort_t* __restrict__ X, const ushort_t* __restrict__ Wg,
    const ushort_t* __restrict__ Wu, const int* __restrict__ pad_off,
    ushort_t* __restrict__ hmid) {
    __shared__ __align__(16) ushort_t lds[4 * 16384];  // 128 KiB
    const int CT = IDIM / 128;                       // 16
    const int NH = HDIM / 32;                        // 32 phases
    int rt, ct;
    sbmap(blockIdx.x, CT / 8, (TOTROWS / 256 / 4) * (CT / 8), rt, ct);
    int row0 = rt * 256, col0 = ct * 128;
    int e;
    if (row0 >= RPAD_MAX) e = 8;
    else {
        if (row0 >= pad_off[NEXP]) return;
        e = 0;
        while (e < 7 && row0 >= pad_off[e + 1]) ++e;
    }
    const ushort_t* wgp = Wg + (size_t)e * IDIM * HDIM;
    const ushort_t* wup = Wu + (size_t)e * IDIM * HDIM;

    const int tid = threadIdx.x, l = tid & 63, w = tid >> 6;
    const int wm = w >> 2, wn = w & 3;
    const int lr = l & 15, lg4 = l >> 4;

    // staging sources (paired-row XOR layout; source pre-swizzled = involution)
    int rA0, kA0, rA1, kA1, rB, kB;
    gdec(tid, rA0, kA0);          // A granules [0,512)   -> rows 0..127
    gdec(512 + tid, rA1, kA1);    // A granules [512,1024)-> rows 128..255
    gdec(tid, rB, kB);            // B granules [0,512)   -> rows 0..127
    const ushort_t* srcA0 = X + (size_t)(row0 + rA0) * HDIM + kA0 * 8;
    const ushort_t* srcA1 = X + (size_t)(row0 + rA1) * HDIM + kA1 * 8;
    const ushort_t* srcBg = wgp + (size_t)(col0 + rB) * HDIM + kB * 8;
    const ushort_t* srcBu = wup + (size_t)(col0 + rB) * HDIM + kB * 8;

    // fragment read constants (round-4 verified, 0 conflicts)
    const int s_slot = (((l & 1) << 2) | lg4) ^ ((l >> 1) & 7);
    const int aob = (wm * 64 + (lr >> 1)) * 64 + s_slot * 8;
    const int bob = (wn * 16 + (lr >> 1)) * 64 + s_slot * 8;

    f32x4 accg[8][2] = {};
    f32x4 accu[8][2] = {};

#define G1_STAGE(h) do { int ko = (h) * 32; int hb_ = ((h) & 3) * 16384;       \
        gload16(srcA0 + ko, &lds[hb_ + tid * 8]);                              \
        gload16(srcA1 + ko, &lds[hb_ + 4096 + tid * 8]);                       \
        gload16(srcBg + ko, &lds[hb_ + 8192 + tid * 8]);                       \
        gload16(srcBu + ko, &lds[hb_ + 12288 + tid * 8]); } while (0)

#define G1_PH(h, VMWAIT, DOSTAGE) do {                                         \
        const int hb = ((h) & 3) * 16384;                                      \
        s16x8 a[8], bg[2], bu[2];                                              \
        _Pragma("unroll")                                                      \
        for (int m = 0; m < 4; ++m) a[m] = *(const s16x8*)&lds[hb + aob + m * 512]; \
        _Pragma("unroll")                                                      \
        for (int n = 0; n < 2; ++n) {                                          \
            bg[n] = *(const s16x8*)&lds[hb + 8192 + bob + n * 512];            \
            bu[n] = *(const s16x8*)&lds[hb + 12288 + bob + n * 512];           \
        }                                                                      \
        _Pragma("unroll")                                                      \
        for (int m = 0; m < 4; ++m) a[4 + m] = *(const s16x8*)&lds[hb + aob + 2048 + m * 512]; \
        SCHB();                                                                \
        if (DOSTAGE) G1_STAGE((h) + 3);                                        \
        LGKM(4);                                                               \
        __builtin_amdgcn_s_setprio(1);                                         \
        _Pragma("unroll")                                                      \
        for (int m = 0; m < 4; ++m) {                                          \
            accg[m][0] = __builtin_amdgcn_mfma_f32_16x16x32_bf16(a[m], bg[0], accg[m][0], 0, 0, 0); \
            accg[m][1] = __builtin_amdgcn_mfma_f32_16x16x32_bf16(a[m], bg[1], accg[m][1], 0, 0, 0); \
            accu[m][0] = __builtin_amdgcn_mfma_f32_16x16x32_bf16(a[m], bu[0], accu[m][0], 0, 0, 0); \
            accu[m][1] = __builtin_amdgcn_mfma_f32_16x16x32_bf16(a[m], bu[1], accu[m][1], 0, 0, 0); \
        }                                                                      \
        __builtin_amdgcn_s_setprio(0);                                         \
        LGKM(0);                                                               \
        __builtin_amdgcn_s_setprio(1);                                         \
        _Pragma("unroll")                                                      \
        for (int m = 0; m < 4; ++m) {                                          \
            accg[4 + m][0] = __builtin_amdgcn_mfma_f32_16x16x32_bf16(a[4 + m], bg[0], accg[4 + m][0], 0, 0, 0); \
            accg[4 + m][1] = __builtin_amdgcn_mfma_f32_16x16x32_bf16(a[4 + m], bg[1], accg[4 + m][1], 0, 0, 0); \
            accu[4 + m][0] = __builtin_amdgcn_mfma_f32_16x16x32_bf16(a[4 + m], bu[0], accu[4 + m][0], 0, 0, 0); \
            accu[4 + m][1] = __builtin_amdgcn_mfma_f32_16x16x32_bf16(a[4 + m], bu[1], accu[4 + m][1], 0, 0, 0); \
        }                                                                      \
        __builtin_amdgcn_s_setprio(0);                                         \
        VMWAIT;                                                                \
        SBAR();                                                                \
    } while (0)

    G1_STAGE(0);
    G1_STAGE(1);
    G1_STAGE(2);
    VMW(8);
    SBAR();
    for (int h = 0; h < NH - 3; ++h) G1_PH(h, VMW(8), 1);
    G1_PH(NH - 3, VMW(4), 0);
    G1_PH(NH - 2, VMW(0), 0);
    G1_PH(NH - 1, VMW(0), 0);

#pragma unroll
    for (int mf = 0; mf < 8; ++mf) {
        int row = row0 + wm * 128 + mf * 16 + lg4 * 4;
#pragma unroll
        for (int nf = 0; nf < 2; ++nf) {
            int col = col0 + wn * 32 + nf * 16 + lr;
#pragma unroll
            for (int rr = 0; rr < 4; ++rr) {
                float g = accg[mf][nf][rr], u = accu[mf][nf][rr];
                float val = g / (1.f + __expf(-g)) * u;
                hmid[(size_t)(row + rr) * IDIM + col] = f2bf(val);
            }
        }
    }
#undef G1_STAGE
#undef G1_PH
}

// ================= GEMM2: out = Hm @ Wd^T (+ hs). BM=256, BN=256, K-step 32,
// ring-4 x 32KB, counted vmcnt(8). Routed 160 blocks / shared 128 blocks.
template <int SHARED>
__global__ __launch_bounds__(512, 2) void gemm2_k(
    const ushort_t* __restrict__ Hm, const ushort_t* __restrict__ Wd,
    const int* __restrict__ pad_off, const int* __restrict__ order,
    const float* __restrict__ hs, float* __restrict__ out, int RT) {
    __shared__ __align__(16) ushort_t lds[4 * 16384];  // 128 KiB
    const int CT = 4;                    // 1024 / 256
    const int NH = IDIM / 32;            // 64 phases
    int nwg = RT * CT;
    int bid = blockIdx.x;
    int q = nwg >> 3, r = nwg & 7;
    int xcd = bid & 7, idx = bid >> 3;
    int wg = (xcd < r ? xcd * (q + 1) : r * (q + 1) + (xcd - r) * q) + idx;
    int rt = wg >> 2, ct = wg & 3;       // rt-major
    int row0 = rt * 256, col0 = ct * 256;
    const ushort_t* wdp;
    if (SHARED) {
        wdp = Wd + (size_t)8 * HDIM * IDIM;
    } else {
        if (row0 >= pad_off[NEXP]) return;
        int e = 0;
        while (e < 7 && row0 >= pad_off[e + 1]) ++e;
        wdp = Wd + (size_t)e * HDIM * IDIM;
    }
    const int tid = threadIdx.x, l = tid & 63, w = tid >> 6;
    const int wm = w >> 2, wn = w & 3;
    const int lr = l & 15, lg4 = l >> 4;

    int rA0, kA0, rA1, kA1;
    gdec(tid, rA0, kA0);
    gdec(512 + tid, rA1, kA1);
    const ushort_t* srcA0 = Hm + (size_t)(row0 + rA0) * IDIM + kA0 * 8;
    const ushort_t* srcA1 = Hm + (size_t)(row0 + rA1) * IDIM + kA1 * 8;
    const ushort_t* srcB0 = wdp + (size_t)(col0 + rA0) * IDIM + kA0 * 8;
    const ushort_t* srcB1 = wdp + (size_t)(col0 + rA1) * IDIM + kA1 * 8;

    const int s_slot = (((l & 1) << 2) | lg4) ^ ((l >> 1) & 7);
    const int aob = (wm * 64 + (lr >> 1)) * 64 + s_slot * 8;
    const int bob = (wn * 32 + (lr >> 1)) * 64 + s_slot * 8;

    f32x4 acc[8][4] = {};

#define G2_STAGE(h) do { int ko = (h) * 32; int hb_ = ((h) & 3) * 16384;       \
        gload16(srcA0 + ko, &lds[hb_ + tid * 8]);                              \
        gload16(srcA1 + ko, &lds[hb_ + 4096 + tid * 8]);                       \
        gload16(srcB0 + ko, &lds[hb_ + 8192 + tid * 8]);                       \
        gload16(srcB1 + ko, &lds[hb_ + 12288 + tid * 8]); } while (0)

#define G2_PH(h, VMWAIT, DOSTAGE) do {                                         \
        const int hb = ((h) & 3) * 16384;                                      \
        s16x8 a[8], b[4];                                                      \
        _Pragma("unroll")                                                      \
        for (int m = 0; m < 4; ++m) a[m] = *(const s16x8*)&lds[hb + aob + m * 512]; \
        _Pragma("unroll")                                                      \
        for (int n = 0; n < 4; ++n) b[n] = *(const s16x8*)&lds[hb + 8192 + bob + n * 512]; \
        _Pragma("unroll")                                                      \
        for (int m = 0; m < 4; ++m) a[4 + m] = *(const s16x8*)&lds[hb + aob + 2048 + m * 512]; \
        SCHB();                                                                \
        if (DOSTAGE) G2_STAGE((h) + 3);                                        \
        LGKM(4);                                                               \
        __builtin_amdgcn_s_setprio(1);                                         \
        _Pragma("unroll")                                                      \
        for (int m = 0; m < 4; ++m)                                            \
            _Pragma("unroll")                                                  \
            for (int n = 0; n < 4; ++n)                                        \
                acc[m][n] = __builtin_amdgcn_mfma_f32_16x16x32_bf16(a[m], b[n], acc[m][n], 0, 0, 0); \
        __builtin_amdgcn_s_setprio(0);                                         \
        LGKM(0);                                                               \
        __builtin_amdgcn_s_setprio(1);                                         \
        _Pragma("unroll")                                                      \
        for (int m = 0; m < 4; ++m)                                            \
            _Pragma("unroll")                                                  \
            for (int n = 0; n < 4; ++n)                                        \
                acc[4 + m][n] = __builtin_amdgcn_mfma_f32_16x16x32_bf16(a[4 + m], b[n], acc[4 + m][n], 0, 0, 0); \
        __builtin_amdgcn_s_setprio(0);                                         \
        VMWAIT;                                                                \
        SBAR();                                                                \
    } while (0)

    G2_STAGE(0);
    G2_STAGE(1);
    G2_STAGE(2);
    VMW(8);
    SBAR();
    for (int h = 0; h < NH - 3; ++h) G2_PH(h, VMW(8), 1);
    G2_PH(NH - 3, VMW(4), 0);
    G2_PH(NH - 2, VMW(0), 0);
    G2_PH(NH - 1, VMW(0), 0);

#pragma unroll
    for (int mf = 0; mf < 8; ++mf) {
        int row = row0 + wm * 128 + mf * 16 + lg4 * 4;
#pragma unroll
        for (int rr = 0; rr < 4; ++rr) {
            int rw_ = row + rr;
            int tok;
            if (SHARED) tok = rw_;               // shared region rows == tokens
            else { tok = order[rw_]; if (tok < 0) continue; }
            size_t ob = (size_t)tok * HDIM;
#pragma unroll
            for (int nf = 0; nf < 4; ++nf) {
                int col = col0 + wn * 64 + nf * 16 + lr;
                if (SHARED) out[ob + col] += hs[ob + col] + acc[mf][nf][rr];
                else        out[ob + col] = acc[mf][nf][rr];
            }
        }
    }
#undef G2_STAGE
#undef G2_PH
}

extern "C" void kernel_launch(void* const* d_in, const int* in_sizes, int n_in,
                              void* d_out, int out_size, void* d_ws, size_t ws_size,
                              hipStream_t stream) {
    const float* hs = (const float*)d_in[0];
    const float* lnw = (const float*)d_in[1];
    const float* lnb = (const float*)d_in[2];
    const float* rw = (const float*)d_in[3];
    const float* gw = (const float*)d_in[4];
    const float* uw = (const float*)d_in[5];
    const float* dw = (const float*)d_in[6];
    const float* shg = (const float*)d_in[7];
    const float* shu = (const float*)d_in[8];
    const float* shd = (const float*)d_in[9];
    float* out = (float*)d_out;

    char* p = (char*)d_ws;
    auto alloc = [&](size_t bytes) {
        void* r = (void*)p;
        p += (bytes + 255) & ~(size_t)255;
        return r;
    };
    ushort_t* xsbuf = (ushort_t*)alloc((size_t)TOTROWS * HDIM * 2);   // routed rows + normed rows
    ushort_t* hmid = (ushort_t*)alloc((size_t)TOTROWS * IDIM * 2);
    ushort_t* gwt = (ushort_t*)alloc((size_t)9 * IDIM * HDIM * 2);    // experts 0-7 + shared(8)
    ushort_t* uwt = (ushort_t*)alloc((size_t)9 * IDIM * HDIM * 2);
    ushort_t* dwt = (ushort_t*)alloc((size_t)9 * HDIM * IDIM * 2);
    int* cnt = (int*)alloc(NEXP * 4);
    int* pad_off = (int*)alloc((NEXP + 1) * 4);
    int* fill = (int*)alloc(NEXP * 4);
    int* top_idx = (int*)alloc(T_TOK * 4);
    float* top_sc = (float*)alloc(T_TOK * 4);
    int* order = (int*)alloc(RPAD_MAX * 4);

    ushort_t* normed = xsbuf + (size_t)RPAD_MAX * HDIM;

    hipMemsetAsync(cnt, 0, NEXP * 4, stream);
    hipMemsetAsync(order, 0xFF, RPAD_MAX * 4, stream);
    hipMemsetAsync(xsbuf, 0, (size_t)RPAD_MAX * HDIM * 2, stream);   // zero pad rows

    // weights transpose+convert (27 matrices)
    tcvt64<<<dim3(IDIM / 64, HDIM / 64, 27), 256, 0, stream>>>(
        gw, shg, uw, shu, dw, shd, gwt, uwt, dwt);

    ln_router<<<T_TOK / 4, 256, 0, stream>>>(hs, lnw, lnb, rw, normed, top_idx, top_sc, cnt);
    scan_k<<<1, 64, 0, stream>>>(cnt, pad_off, fill);
    scatter_k<<<T_TOK / 4, 256, 0, stream>>>(normed, top_idx, top_sc, pad_off, fill, order, xsbuf);

    // fused gemm1 over routed (rows [0,RPAD_MAX)) + shared (rows [RPAD_MAX,TOTROWS))
    {
        int RT = TOTROWS / 256, CT = IDIM / 128;
        gemm1_k<<<RT * CT, 512, 0, stream>>>(xsbuf, gwt, uwt, pad_off, hmid);
    }
    // routed down-proj FIRST: out[tok] = acc (plain store; every token exactly once)
    {
        int RT = RPAD_MAX / 256;  // 40 -> 160 blocks (single round)
        gemm2_k<0><<<RT * 4, 512, 0, stream>>>(
            hmid, dwt, pad_off, order, hs, out, RT);
    }
    // shared down-proj SECOND: out += hs + acc
    {
        int RT = T_TOK / 256;  // 32 -> 128 blocks (single round)
        gemm2_k<1><<<RT * 4, 512, 0, stream>>>(
            hmid + (size_t)RPAD_MAX * IDIM, dwt, pad_off, order, hs, out, RT);
    }
}